// Round 5
// baseline (358.037 us; speedup 1.0000x reference)
//
#include <hip/hip_runtime.h>

#define NN 4
#define CC 20
#define HH 64
#define WW 2048
#define CG 4           // channel groups
#define CPG (CC / CG)  // 5 channels per group
#define PX 4           // pixels per thread

// R4 body (2-chunk windows, VGPR=60, no spills) + ONE structural change:
// the dy loop is made BRANCH-FREE (row index clamped to [0,63], row
// validity folded into mf as a 0/1 factor) and explicitly software-
// pipelined: row r+1's xyz/mask loads are issued before row r's compute.
// Rationale: all pipes <=40% at the hard 4-waves/SIMD TLP cap, and the
// old per-row `continue` branch split the unrolled body into 5 basic
// blocks, blocking cross-row load hoisting (compiler used only 60 of its
// 128-VGPR budget). Straight-line + prefetch converts 5 serial latency
// envelopes per wave into overlapped ones.
// Tripwires: VGPR <= 128, WRITE_SIZE must stay 40960 KB (R1/R3: spill
// cliff costs 2-3x).

struct RowVec {
    int4   mA, mB;
    float4 xA, xB, yA, yB, zA, zB;
};

__device__ __forceinline__ RowVec load_row(const float* __restrict__ xb,
                                           const int* __restrict__ mb,
                                           int rb, int aC, int bC, int hw) {
    RowVec r;
    r.mA = *(const int4*)(mb + rb + aC);
    r.mB = *(const int4*)(mb + rb + bC);
    r.xA = *(const float4*)(xb + 0 * hw + rb + aC);
    r.xB = *(const float4*)(xb + 0 * hw + rb + bC);
    r.yA = *(const float4*)(xb + 1 * hw + rb + aC);
    r.yB = *(const float4*)(xb + 1 * hw + rb + bC);
    r.zA = *(const float4*)(xb + 2 * hw + rb + aC);
    r.zB = *(const float4*)(xb + 2 * hw + rb + bC);
    return r;
}

__global__ __launch_bounds__(256, 4) void lc_xyz_kernel(
    const float* __restrict__ xyz,
    const float* __restrict__ softmax,
    const int* __restrict__ mask,
    float* __restrict__ out)
{
    const int t  = blockIdx.x * blockDim.x + threadIdx.x;  // pixel-quad index: 0..511
    const int h  = blockIdx.y;
    const int nz = blockIdx.z;
    const int n  = nz >> 2;
    const int cg = nz & 3;
    const int hw = HH * WW;
    const int p0 = t * PX;

    const float* xb  = xyz     + (size_t)n * 3  * hw;
    const float* smb = softmax + (size_t)n * CC * hw + (size_t)(cg * CPG) * hw;
    const int*   mb  = mask    + (size_t)n * hw;

    const int ctr = h * WW + p0;
    const float4 cxv = *(const float4*)(xb + 0 * hw + ctr);
    const float4 cyv = *(const float4*)(xb + 1 * hw + ctr);
    const float4 czv = *(const float4*)(xb + 2 * hw + ctr);
    const float cx[PX] = {cxv.x, cxv.y, cxv.z, cxv.w};
    const float cy[PX] = {cyv.x, cyv.y, cyv.z, cyv.w};
    const float cz[PX] = {czv.x, czv.y, czv.z, czv.w};

    float acc[CPG][PX];
#pragma unroll
    for (int c = 0; c < CPG; ++c)
#pragma unroll
        for (int i = 0; i < PX; ++i) acc[c][i] = 0.f;

    // Window slot j=0..7 holds position w = p0-2+j; tap (i,dx) uses j=i+dx.
    // Chunk A at p0-2 covers j=0..3, chunk B at p0+2 covers j=4..7.
    // Edge threads clamp the base; always-valid center slots 2..5 are
    // repaired via cndmask; outer slots 0,1,6,7 are zeroed through mf.
    const int  a0 = p0 - 2;
    const int  b0 = p0 + 2;
    const bool sl = (a0 < 0);
    const bool sr = (b0 > WW - 4);
    const int  aC = sl ? 0 : a0;
    const int  bC = sr ? (WW - 4) : b0;
    const float vfL = sl ? 0.f : 1.f;   // validity of slots 0,1
    const float vfR = sr ? 0.f : 1.f;   // validity of slots 6,7

    // Branch-free row setup: clamped row base (loads always in-bounds),
    // validity factor folded into mf.
    int   rbs[5];
    float vr[5];
#pragma unroll
    for (int r = 0; r < 5; ++r) {
        const int rr = h + r - 2;
        vr[r] = ((unsigned)rr < (unsigned)HH) ? 1.f : 0.f;
        const int rc = rr < 0 ? 0 : (rr > HH - 1 ? HH - 1 : rr);
        rbs[r] = rc * WW;
    }

    RowVec cur = load_row(xb, mb, rbs[0], aC, bC, hw);

#pragma unroll
    for (int r = 0; r < 5; ++r) {
        // Prefetch next row's xyz/mask BEFORE computing this row.
        RowVec nxt;
        if (r < 4) nxt = load_row(xb, mb, rbs[r + 1], aC, bC, hw);

        const int rb = rbs[r];
        const float vrow = vr[r];

        // Window values; slots 0,1,6,7 may hold clamped garbage (mf zeroes them).
        const float xw[8] = {cur.xA.x, cur.xA.y, sl ? cur.xA.x : cur.xA.z, sl ? cur.xA.y : cur.xA.w,
                             sr ? cur.xB.z : cur.xB.x, sr ? cur.xB.w : cur.xB.y, cur.xB.z, cur.xB.w};
        const float yw[8] = {cur.yA.x, cur.yA.y, sl ? cur.yA.x : cur.yA.z, sl ? cur.yA.y : cur.yA.w,
                             sr ? cur.yB.z : cur.yB.x, sr ? cur.yB.w : cur.yB.y, cur.yB.z, cur.yB.w};
        const float zw[8] = {cur.zA.x, cur.zA.y, sl ? cur.zA.x : cur.zA.z, sl ? cur.zA.y : cur.zA.w,
                             sr ? cur.zB.z : cur.zB.x, sr ? cur.zB.w : cur.zB.y, cur.zB.z, cur.zB.w};

        // Mask window with row validity and edge validity folded in.
        const float mf[8] = {
            vrow * vfL * (float)cur.mA.x,
            vrow * vfL * (float)cur.mA.y,
            vrow * (float)(sl ? cur.mA.x : cur.mA.z),
            vrow * (float)(sl ? cur.mA.y : cur.mA.w),
            vrow * (float)(sr ? cur.mB.z : cur.mB.x),
            vrow * (float)(sr ? cur.mB.w : cur.mB.y),
            vrow * vfR * (float)cur.mB.z,
            vrow * vfR * (float)cur.mB.w};

        // Gaussian weights, once per (pixel, tap), shared across channels.
        float g[PX][5];
#pragma unroll
        for (int i = 0; i < PX; ++i) {
#pragma unroll
            for (int dx = 0; dx < 5; ++dx) {
                const int j = i + dx;
                const float ax = xw[j] - cx[i];
                const float ay = yw[j] - cy[i];
                const float az = zw[j] - cz[i];
                const float d2 = ax * ax + ay * ay + az * az;
                g[i][dx] = mf[j] * __expf(-0.5f * d2);
            }
        }

        // Channel loop: 2 float4 loads + 20 FMA per channel.
#pragma unroll
        for (int c = 0; c < CPG; ++c) {
            const float* sp = smb + (size_t)c * hw + rb;
            const float4 sA = *(const float4*)(sp + aC);
            const float4 sB = *(const float4*)(sp + bC);
            const float sw[8] = {sA.x, sA.y, sl ? sA.x : sA.z, sl ? sA.y : sA.w,
                                 sr ? sB.z : sB.x, sr ? sB.w : sB.y, sB.z, sB.w};
#pragma unroll
            for (int i = 0; i < PX; ++i) {
                float a = acc[c][i];
#pragma unroll
                for (int dx = 0; dx < 5; ++dx)
                    a = fmaf(g[i][dx], sw[i + dx], a);
                acc[c][i] = a;
            }
        }

        if (r < 4) cur = nxt;
    }

    float* ob = out + (size_t)n * CC * hw + (size_t)(cg * CPG) * hw + ctr;
#pragma unroll
    for (int c = 0; c < CPG; ++c)
        *(float4*)(ob + (size_t)c * hw) =
            make_float4(acc[c][0], acc[c][1], acc[c][2], acc[c][3]);
}

extern "C" void kernel_launch(void* const* d_in, const int* in_sizes, int n_in,
                              void* d_out, int out_size, void* d_ws, size_t ws_size,
                              hipStream_t stream) {
    const float* xyz     = (const float*)d_in[0];
    const float* softmax = (const float*)d_in[1];
    const int*   mask    = (const int*)d_in[2];
    float*       out     = (float*)d_out;

    dim3 block(256, 1, 1);
    dim3 grid(WW / (PX * 256), HH, NN * CG);   // 2 x 64 x 16 = 2048 blocks
    hipLaunchKernelGGL(lc_xyz_kernel, grid, block, 0, stream,
                       xyz, softmax, mask, out);
}

// Round 7
// 153.685 us; speedup vs baseline: 2.3297x; 2.3297x over previous
//
#include <hip/hip_runtime.h>

#define NN 4
#define CC 20
#define HH 64
#define WW 2048
#define CG 2           // channel groups (was 4): halves redundant g-compute
#define CPG (CC / CG)  // 10 channels per group
#define PX 4           // pixels per thread

// EXACT R0 body (3-chunk aligned window loads, branched dy loop, (256,4),
// 3D grid, no swizzle — proven 58us/dispatch, VGPR=64, zero spill) with ONE
// change: CG 4->2 (CPG 5->10). Each Gaussian weight set g[px][tap] was
// computed by 4 blocks (one per channel group); now by 2. Per px-channel:
// VALU 15->10 (-33%), VMEM 1.35->1.05 (-22%). Grid 2048->1024 blocks =
// exactly one 4-blocks/CU tranche. Register growth is confined to +20 acc
// regs (sw transient reuses its slot per channel iteration).
// Tripwire: WRITE_SIZE must stay 40960 KB and VGPR <= ~100; R1/R3/R5 all
// showed the compiler spills aggregates instead of using VGPR headroom —
// if it spills, CG=4/R0 is the final answer.
// (Resubmission of R6 — previous run died on container acquisition,
// hypothesis untested.)
__global__ __launch_bounds__(256, 4) void lc_xyz_kernel(
    const float* __restrict__ xyz,
    const float* __restrict__ softmax,
    const int* __restrict__ mask,
    float* __restrict__ out)
{
    const int t  = blockIdx.x * blockDim.x + threadIdx.x;  // pixel-quad index in row
    const int h  = blockIdx.y;
    const int nz = blockIdx.z;            // 0..7
    const int n  = nz >> 1;
    const int cg = nz & 1;
    const int hw = HH * WW;
    const int p0 = t * PX;

    const float* xb  = xyz     + (size_t)n * 3  * hw;
    const float* smb = softmax + (size_t)n * CC * hw + (size_t)(cg * CPG) * hw;
    const int*   mb  = mask    + (size_t)n * hw;

    const int ctr = h * WW + p0;
    const float4 cxv = *(const float4*)(xb + 0 * hw + ctr);
    const float4 cyv = *(const float4*)(xb + 1 * hw + ctr);
    const float4 czv = *(const float4*)(xb + 2 * hw + ctr);
    const float cx[PX] = {cxv.x, cxv.y, cxv.z, cxv.w};
    const float cy[PX] = {cyv.x, cyv.y, cyv.z, cyv.w};
    const float cz[PX] = {czv.x, czv.y, czv.z, czv.w};

    float acc[CPG][PX];
#pragma unroll
    for (int c = 0; c < CPG; ++c)
#pragma unroll
        for (int i = 0; i < PX; ++i) acc[c][i] = 0.f;

    // Window indices j=0..11 map to w = p0-4+j; taps use j = i+dx+2 in [2,9].
    // Aligned 16B chunks at p0-4, p0, p0+4; edge chunks clamped (their taps
    // are zeroed via validity, and all VALID taps come from unclamped chunks).
    int c0 = p0 - 4; if (c0 < 0) c0 = 0;
    const int c1 = p0;
    int c2 = p0 + 4; if (c2 > WW - 4) c2 = WW - 4;

    float vf[12];
#pragma unroll
    for (int j = 2; j <= 9; ++j)
        vf[j] = ((unsigned)(p0 - 4 + j) < (unsigned)WW) ? 1.f : 0.f;

#pragma unroll
    for (int dy = -2; dy <= 2; ++dy) {
        const int row = h + dy;
        if ((unsigned)row >= (unsigned)HH) continue;   // wave-uniform
        const int rb = row * WW;

        // Batched independent row loads: 3 int4 + 9 float4.
        const int4 m0 = *(const int4*)(mb + rb + c0);
        const int4 m1 = *(const int4*)(mb + rb + c1);
        const int4 m2 = *(const int4*)(mb + rb + c2);
        const float4 x0 = *(const float4*)(xb + 0 * hw + rb + c0);
        const float4 x1 = *(const float4*)(xb + 0 * hw + rb + c1);
        const float4 x2 = *(const float4*)(xb + 0 * hw + rb + c2);
        const float4 y0 = *(const float4*)(xb + 1 * hw + rb + c0);
        const float4 y1 = *(const float4*)(xb + 1 * hw + rb + c1);
        const float4 y2 = *(const float4*)(xb + 1 * hw + rb + c2);
        const float4 z0 = *(const float4*)(xb + 2 * hw + rb + c0);
        const float4 z1 = *(const float4*)(xb + 2 * hw + rb + c1);
        const float4 z2 = *(const float4*)(xb + 2 * hw + rb + c2);

        const float xw[12] = {x0.x,x0.y,x0.z,x0.w, x1.x,x1.y,x1.z,x1.w, x2.x,x2.y,x2.z,x2.w};
        const float yw[12] = {y0.x,y0.y,y0.z,y0.w, y1.x,y1.y,y1.z,y1.w, y2.x,y2.y,y2.z,y2.w};
        const float zw[12] = {z0.x,z0.y,z0.z,z0.w, z1.x,z1.y,z1.z,z1.w, z2.x,z2.y,z2.z,z2.w};
        const int   mi[12] = {m0.x,m0.y,m0.z,m0.w, m1.x,m1.y,m1.z,m1.w, m2.x,m2.y,m2.z,m2.w};

        float mf[12];
#pragma unroll
        for (int j = 2; j <= 9; ++j) mf[j] = vf[j] * (float)mi[j];

        // Gaussian weights, once per (pixel, tap), shared across channels.
        float g[PX][5];
#pragma unroll
        for (int i = 0; i < PX; ++i) {
#pragma unroll
            for (int dx = 0; dx < 5; ++dx) {
                const int j = i + dx + 2;
                const float ax = xw[j] - cx[i];
                const float ay = yw[j] - cy[i];
                const float az = zw[j] - cz[i];
                const float d2 = ax * ax + ay * ay + az * az;
                g[i][dx] = mf[j] * __expf(-0.5f * d2);
            }
        }

        // Channel loop: 3 float4 loads + 20 FMA per channel (now 10 channels).
#pragma unroll
        for (int c = 0; c < CPG; ++c) {
            const float* sp = smb + (size_t)c * hw + rb;
            const float4 s0 = *(const float4*)(sp + c0);
            const float4 s1 = *(const float4*)(sp + c1);
            const float4 s2 = *(const float4*)(sp + c2);
            const float sw[12] = {s0.x,s0.y,s0.z,s0.w, s1.x,s1.y,s1.z,s1.w, s2.x,s2.y,s2.z,s2.w};
#pragma unroll
            for (int i = 0; i < PX; ++i) {
                float a = acc[c][i];
#pragma unroll
                for (int dx = 0; dx < 5; ++dx)
                    a = fmaf(g[i][dx], sw[i + dx + 2], a);
                acc[c][i] = a;
            }
        }
    }

    float* ob = out + (size_t)n * CC * hw + (size_t)(cg * CPG) * hw + ctr;
#pragma unroll
    for (int c = 0; c < CPG; ++c)
        *(float4*)(ob + (size_t)c * hw) =
            make_float4(acc[c][0], acc[c][1], acc[c][2], acc[c][3]);
}

extern "C" void kernel_launch(void* const* d_in, const int* in_sizes, int n_in,
                              void* d_out, int out_size, void* d_ws, size_t ws_size,
                              hipStream_t stream) {
    const float* xyz     = (const float*)d_in[0];
    const float* softmax = (const float*)d_in[1];
    const int*   mask    = (const int*)d_in[2];
    float*       out     = (float*)d_out;

    dim3 block(256, 1, 1);
    dim3 grid(WW / (PX * 256), HH, NN * CG);   // 2 x 64 x 8 = 1024 blocks
    hipLaunchKernelGGL(lc_xyz_kernel, grid, block, 0, stream,
                       xyz, softmax, mask, out);
}